// Round 8
// baseline (171.545 us; speedup 1.0000x reference)
//
#include <hip/hip_runtime.h>
#include <hip/hip_bf16.h>
#include <math.h>

#define NB 65536
#define DIN 1024
#define NQ 64
#define DOUT 1024

typedef __attribute__((ext_vector_type(8))) short bf16x8;
typedef __attribute__((ext_vector_type(4))) float f32x4;
typedef unsigned short u16;

__device__ __forceinline__ u16 f2bf(float f) {
    union { float f; unsigned u; } v; v.f = f;
    return (u16)((v.u + 0x7fffu + ((v.u >> 16) & 1u)) >> 16);
}

// ---- kP: bf16 weights in FRAGMENT-MAJOR order + per-q constants -------------
// Wbf : chunk t(32), frag n(4), lane l(64), j(8):
//       Wbf[((t*4+n)*64+l)*8+j] = W_in[n*16+(l&15)][t*32+(l>>4)*8+j]
// Wobf: tile n(64), kf(2), lane l(64), j(8):
//       Wobf[((n*2+kf)*64+l)*8+j] = W_out[n*16+(l&15)][kf*32+(l>>4)*8+j]
__global__ __launch_bounds__(256) void kP(const float* __restrict__ W_in,
                                          const float* __restrict__ W_out,
                                          const float* __restrict__ qp,
                                          u16* __restrict__ Wbf,
                                          u16* __restrict__ Wobf,
                                          float* __restrict__ cp0,
                                          float* __restrict__ cq) {
    int tid = blockIdx.x * 256 + threadIdx.x;       // 0..65535
    {
        int j = tid & 7, l = (tid >> 3) & 63, n = (tid >> 9) & 3, c = tid >> 11;
        int row = n * 16 + (l & 15);
        int k   = c * 32 + (l >> 4) * 8 + j;
        Wbf[tid] = f2bf(W_in[row * DIN + k]);
    }
    {
        int j = tid & 7, l = (tid >> 3) & 63, kf = (tid >> 9) & 1, n = tid >> 10;
        int col = n * 16 + (l & 15);
        int k   = kf * 32 + (l >> 4) * 8 + j;
        Wobf[tid] = f2bf(W_out[col * NQ + k]);
    }
    if (tid < NQ) {
        cp0[tid] = cosf(qp[tid * 3 + 0]);
        cq[tid]  = sinf(qp[tid * 3 + 1]) * cosf(qp[tid * 3 + 2]);
    }
}

// ---- kF: fused, all-asm VMEM, counted vmcnt, ZERO in-loop barriers ----------
// 1024 blocks x 256 threads (4 independent waves; wave owns 16 rows).
// __launch_bounds__(256,4): VGPR cap 128 so the register ring stays LIVE
// (prior rounds: default occupancy heuristic capped at ~56 -> compiler
// serialized every load with its own waitcnt; ring silently deleted).
// Phase B waits use the newer-ops formula INCLUDING stores (gfx9: stores
// increment vmcnt): steady vmcnt(24) = 16 stores + 8 loads in flight.
__global__ __launch_bounds__(256, 4) void kF(const float* __restrict__ x,
                                             const u16* __restrict__ Wbf,
                                             const float* __restrict__ b_in,
                                             const float* __restrict__ cp0,
                                             const float* __restrict__ cq,
                                             const u16* __restrict__ Wobf,
                                             const float* __restrict__ b_out,
                                             float* __restrict__ out) {
    __shared__ u16   st[4][16][72];     // 9216 B, wave-private slices
    __shared__ float boutL[DOUT];       // 4096 B
    __shared__ float binL[NQ], cp0L[NQ], cqL[NQ];

    const int tid = threadIdx.x;
    const int w = tid >> 6, l = tid & 63;
    const int r = l & 15, kg = l >> 4;
    const int row0 = blockIdx.x * 64;

    // stage small constants to LDS (the ONLY compiler VMEM in this kernel)
    *(float4*)(boutL + tid * 4) = *(const float4*)(b_out + tid * 4);
    if (tid < NQ) { binL[tid] = b_in[tid]; cp0L[tid] = cp0[tid]; cqL[tid] = cq[tid]; }
    __syncthreads();

    // fixed addresses: all per-chunk variation goes into saddr (scalar) or imm
    const char* xS   = (const char*)x + (size_t)row0 * DIN * 4;
    const char* outS = (const char*)out + (size_t)row0 * DOUT * 4;
    const unsigned voff_x   = (unsigned)(w * 16 + r) * (DIN * 4) + kg * 32;
    const unsigned voff_l16 = (unsigned)l * 16;
    unsigned vo[4];
    #pragma unroll
    for (int i = 0; i < 4; i++)
        vo[i] = (unsigned)(w * 16 + kg * 4 + i) * (DOUT * 4) + r * 4;

#define LDX(slot, t) { \
    asm volatile("global_load_dwordx4 %0, %1, %2 offset:%3" \
        : "=v"(xr[slot][0]) : "v"(voff_x), "s"(xS), "i"((t) * 128)); \
    asm volatile("global_load_dwordx4 %0, %1, %2 offset:%3" \
        : "=v"(xr[slot][1]) : "v"(voff_x), "s"(xS), "i"((t) * 128 + 16)); }
#define LDW(slot, t) { const char* wS_ = (const char*)Wbf + (t) * 4096; \
    asm volatile("global_load_dwordx4 %0, %1, %2 offset:0"    : "=v"(wbr[slot][0]) : "v"(voff_l16), "s"(wS_)); \
    asm volatile("global_load_dwordx4 %0, %1, %2 offset:1024" : "=v"(wbr[slot][1]) : "v"(voff_l16), "s"(wS_)); \
    asm volatile("global_load_dwordx4 %0, %1, %2 offset:2048" : "=v"(wbr[slot][2]) : "v"(voff_l16), "s"(wS_)); \
    asm volatile("global_load_dwordx4 %0, %1, %2 offset:3072" : "=v"(wbr[slot][3]) : "v"(voff_l16), "s"(wS_)); }
#define PBLOAD(slot, g) { const char* oS_ = (const char*)Wobf + (g) * 4096; \
    asm volatile("global_load_dwordx4 %0, %1, %2 offset:0"    : "=v"(wob[slot][0][0]) : "v"(voff_l16), "s"(oS_)); \
    asm volatile("global_load_dwordx4 %0, %1, %2 offset:1024" : "=v"(wob[slot][0][1]) : "v"(voff_l16), "s"(oS_)); \
    asm volatile("global_load_dwordx4 %0, %1, %2 offset:2048" : "=v"(wob[slot][1][0]) : "v"(voff_l16), "s"(oS_)); \
    asm volatile("global_load_dwordx4 %0, %1, %2 offset:3072" : "=v"(wob[slot][1][1]) : "v"(voff_l16), "s"(oS_)); }

    // ---------------- Phase A: GEMM1, register ring, depth 2 ----------------
    f32x4 acc[4] = {f32x4{0,0,0,0}, f32x4{0,0,0,0}, f32x4{0,0,0,0}, f32x4{0,0,0,0}};
    float4 xr[3][2];
    bf16x8 wbr[3][4];

    LDX(0, 0) LDW(0, 0)
    LDX(1, 1) LDW(1, 1)

    #pragma unroll
    for (int t = 0; t < 32; ++t) {
        const int s = t % 3, s2 = (t + 2) % 3;
        if (t + 2 < 32) { LDX(s2, t + 2) LDW(s2, t + 2) }
        __builtin_amdgcn_sched_barrier(0);
        if (t < 30)       asm volatile("s_waitcnt vmcnt(12)" ::: "memory");
        else if (t == 30) asm volatile("s_waitcnt vmcnt(6)"  ::: "memory");
        else              asm volatile("s_waitcnt vmcnt(0)"  ::: "memory");
        __builtin_amdgcn_sched_barrier(0);
        union { bf16x8 v; unsigned u[4]; } a;
        asm("v_cvt_pk_bf16_f32 %0, %1, %2" : "=v"(a.u[0]) : "v"(xr[s][0].x), "v"(xr[s][0].y));
        asm("v_cvt_pk_bf16_f32 %0, %1, %2" : "=v"(a.u[1]) : "v"(xr[s][0].z), "v"(xr[s][0].w));
        asm("v_cvt_pk_bf16_f32 %0, %1, %2" : "=v"(a.u[2]) : "v"(xr[s][1].x), "v"(xr[s][1].y));
        asm("v_cvt_pk_bf16_f32 %0, %1, %2" : "=v"(a.u[3]) : "v"(xr[s][1].z), "v"(xr[s][1].w));
        #pragma unroll
        for (int n = 0; n < 4; ++n)
            acc[n] = __builtin_amdgcn_mfma_f32_16x16x32_bf16(a.v, wbr[s][n], acc[n], 0, 0, 0);
    }

    // ---- issue phase-B groups 0,1 now; they fly during the epilogue ----
    bf16x8 wob[3][2][2];
    PBLOAD(0, 0) PBLOAD(1, 1)
    __builtin_amdgcn_sched_barrier(0);

    // ---------------- quantum epilogue -> st (wave-private, no barrier) -----
    #pragma unroll
    for (int n = 0; n < 4; ++n) {
        int q = n * 16 + r;
        float bi = binL[q], c0q = cp0L[q], c1q = cqL[q];
        #pragma unroll
        for (int i = 0; i < 4; ++i) {
            float av = acc[n][i] + bi;
            float e2 = __builtin_amdgcn_exp2f(av * 2.8853900817779268f);
            float th = 1.0f - 2.0f * __builtin_amdgcn_rcpf(e2 + 1.0f);
            float sv = __builtin_amdgcn_cosf(th * 0.25f) * c0q + c1q;
            st[w][kg * 4 + i][q] = f2bf(sv);
        }
    }
    bf16x8 sa0 = *(const bf16x8*)&st[w][r][kg * 8];
    bf16x8 sa1 = *(const bf16x8*)&st[w][r][32 + kg * 8];

    // ---------------- Phase B: GEMM2, 32 groups of 2 tiles ------------------
    // wait N(g) = #vmcnt-ops issued after group-g's loads:
    //   stores(g-2)+stores(g-1) [8 each, if they exist] + loads(g+1)+loads(g+2)
    #pragma unroll
    for (int g = 0; g < 32; ++g) {
        const int s = g % 3, s2 = (g + 2) % 3;
        if (g + 2 < 32) { PBLOAD(s2, g + 2) }
        __builtin_amdgcn_sched_barrier(0);
        if (g == 0)       asm volatile("s_waitcnt vmcnt(8)"  ::: "memory");
        else if (g == 1)  asm volatile("s_waitcnt vmcnt(16)" ::: "memory");
        else if (g < 30)  asm volatile("s_waitcnt vmcnt(24)" ::: "memory");
        else if (g == 30) asm volatile("s_waitcnt vmcnt(20)" ::: "memory");
        else              asm volatile("s_waitcnt vmcnt(16)" ::: "memory");
        __builtin_amdgcn_sched_barrier(0);
        #pragma unroll
        for (int ti = 0; ti < 2; ++ti) {
            const int tile = g * 2 + ti;
            f32x4 a2 = {0.0f, 0.0f, 0.0f, 0.0f};
            a2 = __builtin_amdgcn_mfma_f32_16x16x32_bf16(sa0, wob[s][ti][0], a2, 0, 0, 0);
            a2 = __builtin_amdgcn_mfma_f32_16x16x32_bf16(sa1, wob[s][ti][1], a2, 0, 0, 0);
            float bo = boutL[tile * 16 + r];
            #pragma unroll
            for (int i = 0; i < 4; ++i) {
                float d = a2[i] + bo;
                asm volatile("global_store_dword %0, %1, %2 offset:%3"
                             :: "v"(vo[i]), "v"(d), "s"(outS), "i"(tile * 64) : "memory");
            }
        }
    }
#undef LDX
#undef LDW
#undef PBLOAD
}

extern "C" void kernel_launch(void* const* d_in, const int* in_sizes, int n_in,
                              void* d_out, int out_size, void* d_ws, size_t ws_size,
                              hipStream_t stream) {
    const float* x    = (const float*)d_in[0];
    const float* W_in = (const float*)d_in[1];
    const float* b_in = (const float*)d_in[2];
    const float* qp   = (const float*)d_in[3];
    const float* W_out= (const float*)d_in[4];
    const float* b_out= (const float*)d_in[5];
    float* out = (float*)d_out;

    char* ws = (char*)d_ws;
    u16*   Wbf  = (u16*)(ws);              // 128 KB fragment-major W_in
    u16*   Wobf = (u16*)(ws + 131072);     // 128 KB fragment-major W_out
    float* cp0  = (float*)(ws + 262144);   // 256 B
    float* cq   = (float*)(ws + 262400);   // 256 B

    kP<<<256, 256, 0, stream>>>(W_in, W_out, qp, Wbf, Wobf, cp0, cq);
    kF<<<NB / 64, 256, 0, stream>>>(x, Wbf, b_in, cp0, cq, Wobf, b_out, out);
}

// Round 9
// 158.099 us; speedup vs baseline: 1.0851x; 1.0851x over previous
//
#include <hip/hip_runtime.h>
#include <hip/hip_bf16.h>
#include <math.h>

#define NB 65536
#define DIN 1024
#define NQ 64
#define DOUT 1024

typedef __attribute__((ext_vector_type(8))) short bf16x8;
typedef __attribute__((ext_vector_type(4))) float f32x4;
typedef unsigned short u16;

__device__ __forceinline__ u16 f2bf(float f) {
    union { float f; unsigned u; } v; v.f = f;
    return (u16)((v.u + 0x7fffu + ((v.u >> 16) & 1u)) >> 16);
}

// async global->LDS DMA. dest = wave-uniform base + lane*size. vmcnt-tracked.
__device__ __forceinline__ void gll16(const void* g, void* l) {
    __builtin_amdgcn_global_load_lds(
        (const __attribute__((address_space(1))) unsigned int*)g,
        (__attribute__((address_space(3))) unsigned int*)l, 16, 0, 0);
}
__device__ __forceinline__ void gll4(const void* g, void* l) {
    __builtin_amdgcn_global_load_lds(
        (const __attribute__((address_space(1))) unsigned int*)g,
        (__attribute__((address_space(3))) unsigned int*)l, 4, 0, 0);
}

// ---- kP: bf16 weights in FRAGMENT-MAJOR order + per-q constants -------------
// Wbf : chunk t(32), frag n(4), lane l(64), j(8):
//       Wbf[((t*4+n)*64+l)*8+j] = W_in[n*16+(l&15)][t*32+(l>>4)*8+j]
// Wobf: tile n(64), kf(2), lane l(64), j(8):
//       Wobf[((n*2+kf)*64+l)*8+j] = W_out[n*16+(l&15)][kf*32+(l>>4)*8+j]
__global__ __launch_bounds__(256) void kP(const float* __restrict__ W_in,
                                          const float* __restrict__ W_out,
                                          const float* __restrict__ qp,
                                          u16* __restrict__ Wbf,
                                          u16* __restrict__ Wobf,
                                          float* __restrict__ cp0,
                                          float* __restrict__ cq) {
    int tid = blockIdx.x * 256 + threadIdx.x;       // 0..65535
    {
        int j = tid & 7, l = (tid >> 3) & 63, n = (tid >> 9) & 3, c = tid >> 11;
        int row = n * 16 + (l & 15);
        int k   = c * 32 + (l >> 4) * 8 + j;
        Wbf[tid] = f2bf(W_in[row * DIN + k]);
    }
    {
        int j = tid & 7, l = (tid >> 3) & 63, kf = (tid >> 9) & 1, n = tid >> 10;
        int col = n * 16 + (l & 15);
        int k   = kf * 32 + (l >> 4) * 8 + j;
        Wobf[tid] = f2bf(W_out[col * NQ + k]);
    }
    if (tid < NQ) {
        cp0[tid] = cosf(qp[tid * 3 + 0]);
        cq[tid]  = sinf(qp[tid * 3 + 1]) * cosf(qp[tid * 3 + 2]);
    }
}

// ---- kF: 1-wave blocks, wave-private LDS DMA rings, counted vmcnt -----------
// 4096 blocks x 64 threads. Wave owns 16 rows. ALL VMEM = gll16/asm stores ->
// exact vmcnt accounting; pipeline depth lives in LDS (allocator-proof).
// Phase A: 32 chunks BK=32, ring depth 3, steady wait vmcnt(12) (2 chunks in
// flight, NEVER drain). Phase B: 32 groups of 2 n-tiles, steady vmcnt(24)
// (= 16 stores + 8 loads newer than the group being consumed).
__global__ __launch_bounds__(64) void kF(const float* __restrict__ x,
                                         const u16* __restrict__ Wbf,
                                         const float* __restrict__ b_in,
                                         const float* __restrict__ cp0,
                                         const float* __restrict__ cq,
                                         const u16* __restrict__ Wobf,
                                         const float* __restrict__ b_out,
                                         float* __restrict__ out) {
    __shared__ __align__(16) char  ring[3 * 6144];   // A: 3x(2KB x + 4KB Wb); B: 3x4KB Wob
    __shared__ __align__(16) u16   st[16][72];
    __shared__ __align__(16) float boutL[DOUT];
    __shared__ __align__(16) float binL[NQ], cp0L[NQ], cqL[NQ];

    const int l = threadIdx.x;           // lane 0..63
    const int r = l & 15, kg = l >> 4;
    const int row0 = blockIdx.x * 16;

    // ---- prologue: stage constants (7 vmcnt ops, oldest) ----
    gll4(b_in + l, binL);
    gll4(cp0 + l, cp0L);
    gll4(cq  + l, cqL);
    gll16(b_out + l * 4 +   0, (char*)boutL);
    gll16(b_out + l * 4 + 256, (char*)boutL + 1024);
    gll16(b_out + l * 4 + 512, (char*)boutL + 2048);
    gll16(b_out + l * 4 + 768, (char*)boutL + 3072);

    // x sources: DMA1 rows 0..7, DMA2 rows 8..15; slot pre-swizzled so LDS
    // holds LDS[row][s_stored] = x[row][(s_stored ^ (row&7))*16 ..] per chunk.
    const char* xs1 = (const char*)x + (size_t)(row0 + (l >> 3)) * (DIN * 4)
                                     + (size_t)((((l & 7) ^ (l >> 3))) * 16);
    const char* xs2 = xs1 + (size_t)8 * DIN * 4;
    const char* wsrc = (const char*)Wbf  + l * 16;
    const char* osrc = (const char*)Wobf + l * 16;

#define STAGE_A(t) { char* buf_ = ring + ((t) % 3) * 6144; \
    gll16(xs1 + (size_t)(t) * 128, buf_); \
    gll16(xs2 + (size_t)(t) * 128, buf_ + 1024); \
    const char* ws_ = wsrc + (size_t)(t) * 4096; \
    gll16(ws_,        buf_ + 2048); \
    gll16(ws_ + 1024, buf_ + 3072); \
    gll16(ws_ + 2048, buf_ + 4096); \
    gll16(ws_ + 3072, buf_ + 5120); }

#define STAGE_B(g) { char* ob_ = ring + ((g) % 3) * 4096; \
    const char* os_ = osrc + (size_t)(g) * 4096; \
    gll16(os_,        ob_); \
    gll16(os_ + 1024, ob_ + 1024); \
    gll16(os_ + 2048, ob_ + 2048); \
    gll16(os_ + 3072, ob_ + 3072); }

    STAGE_A(0) STAGE_A(1)

    // ---------------- Phase A: GEMM1 ----------------
    f32x4 acc[4] = {f32x4{0,0,0,0}, f32x4{0,0,0,0}, f32x4{0,0,0,0}, f32x4{0,0,0,0}};
    const int sA = (2 * kg) ^ (r & 7);       // stored slot of logical slot 2kg
    const int sB = sA ^ 1;                   // stored slot of logical slot 2kg+1

    #pragma unroll
    for (int t = 0; t < 32; ++t) {
        if (t <= 29) STAGE_A(t + 2)
        if (t <= 29)      asm volatile("s_waitcnt vmcnt(12)" ::: "memory");
        else if (t == 30) asm volatile("s_waitcnt vmcnt(6)"  ::: "memory");
        else              asm volatile("s_waitcnt vmcnt(0)"  ::: "memory");
        const char* buf = ring + (t % 3) * 6144;
        const char* xrow = buf + (r >> 3) * 1024 + (r & 7) * 128;
        float4 xa = *(const float4*)(xrow + sA * 16);   // k = kg*8 + 0..3
        float4 xb = *(const float4*)(xrow + sB * 16);   // k = kg*8 + 4..7
        union { bf16x8 v; unsigned u[4]; } a;
        asm("v_cvt_pk_bf16_f32 %0, %1, %2" : "=v"(a.u[0]) : "v"(xa.x), "v"(xa.y));
        asm("v_cvt_pk_bf16_f32 %0, %1, %2" : "=v"(a.u[1]) : "v"(xa.z), "v"(xa.w));
        asm("v_cvt_pk_bf16_f32 %0, %1, %2" : "=v"(a.u[2]) : "v"(xb.x), "v"(xb.y));
        asm("v_cvt_pk_bf16_f32 %0, %1, %2" : "=v"(a.u[3]) : "v"(xb.z), "v"(xb.w));
        #pragma unroll
        for (int n = 0; n < 4; ++n) {
            bf16x8 b = *(const bf16x8*)(buf + 2048 + n * 1024 + l * 16);
            acc[n] = __builtin_amdgcn_mfma_f32_16x16x32_bf16(a.v, b, acc[n], 0, 0, 0);
        }
    }

    // chunk-31 ds_reads are consumed (compiler lgkm-waits before the MFMAs
    // above), so the ring is safe to overwrite: start phase-B prefetch now.
    STAGE_B(0) STAGE_B(1)

    // ---------------- quantum epilogue -> st (wave-private) ----------------
    #pragma unroll
    for (int n = 0; n < 4; ++n) {
        int q = n * 16 + r;
        float bi = binL[q], c0q = cp0L[q], c1q = cqL[q];
        #pragma unroll
        for (int i = 0; i < 4; ++i) {
            float av = acc[n][i] + bi;
            float e2 = __builtin_amdgcn_exp2f(av * 2.8853900817779268f);
            float th = 1.0f - 2.0f * __builtin_amdgcn_rcpf(e2 + 1.0f);
            float sv = __builtin_amdgcn_cosf(th * 0.25f) * c0q + c1q;
            st[kg * 4 + i][q] = f2bf(sv);
        }
    }
    bf16x8 sa0 = *(const bf16x8*)&st[r][kg * 8];
    bf16x8 sa1 = *(const bf16x8*)&st[r][32 + kg * 8];

    // ---------------- Phase B: GEMM2 ----------------
    const char* outS = (const char*)out + (size_t)row0 * DOUT * 4;
    unsigned vo[4];
    #pragma unroll
    for (int i = 0; i < 4; ++i)
        vo[i] = (unsigned)(kg * 4 + i) * (DOUT * 4) + r * 4;

    #pragma unroll
    for (int g = 0; g < 32; ++g) {
        if (g <= 29) STAGE_B(g + 2)
        // newer-than-group-g ops: loads of g+1,g+2 + stores of g-2,g-1
        if (g == 0)       asm volatile("s_waitcnt vmcnt(8)"  ::: "memory");
        else if (g == 1)  asm volatile("s_waitcnt vmcnt(16)" ::: "memory");
        else if (g <= 29) asm volatile("s_waitcnt vmcnt(24)" ::: "memory");
        else if (g == 30) asm volatile("s_waitcnt vmcnt(20)" ::: "memory");
        else              asm volatile("s_waitcnt vmcnt(16)" ::: "memory");
        const char* ob = ring + (g % 3) * 4096;
        #pragma unroll
        for (int ti = 0; ti < 2; ++ti) {
            const int tile = g * 2 + ti;
            bf16x8 b0 = *(const bf16x8*)(ob + ti * 2048 + l * 16);
            bf16x8 b1 = *(const bf16x8*)(ob + ti * 2048 + 1024 + l * 16);
            f32x4 a2 = {0.0f, 0.0f, 0.0f, 0.0f};
            a2 = __builtin_amdgcn_mfma_f32_16x16x32_bf16(sa0, b0, a2, 0, 0, 0);
            a2 = __builtin_amdgcn_mfma_f32_16x16x32_bf16(sa1, b1, a2, 0, 0, 0);
            float bo = boutL[tile * 16 + r];
            #pragma unroll
            for (int i = 0; i < 4; ++i) {
                float d = a2[i] + bo;
                asm volatile("global_store_dword %0, %1, %2 offset:%3"
                             :: "v"(vo[i]), "v"(d), "s"(outS), "i"(tile * 64) : "memory");
            }
        }
    }
#undef STAGE_A
#undef STAGE_B
}

extern "C" void kernel_launch(void* const* d_in, const int* in_sizes, int n_in,
                              void* d_out, int out_size, void* d_ws, size_t ws_size,
                              hipStream_t stream) {
    const float* x    = (const float*)d_in[0];
    const float* W_in = (const float*)d_in[1];
    const float* b_in = (const float*)d_in[2];
    const float* qp   = (const float*)d_in[3];
    const float* W_out= (const float*)d_in[4];
    const float* b_out= (const float*)d_in[5];
    float* out = (float*)d_out;

    char* ws = (char*)d_ws;
    u16*   Wbf  = (u16*)(ws);              // 128 KB fragment-major W_in
    u16*   Wobf = (u16*)(ws + 131072);     // 128 KB fragment-major W_out
    float* cp0  = (float*)(ws + 262144);   // 256 B
    float* cq   = (float*)(ws + 262400);   // 256 B

    kP<<<256, 256, 0, stream>>>(W_in, W_out, qp, Wbf, Wobf, cp0, cq);
    kF<<<NB / 16, 64, 0, stream>>>(x, Wbf, b_in, cp0, cq, Wobf, b_out, out);
}